// Round 3
// baseline (1613.657 us; speedup 1.0000x reference)
//
#include <hip/hip_runtime.h>
#include <hip/hip_bf16.h>
#include <cstdint>

// B=8, C=256, N=4096 spatial self-attention.
// R2: 32 queries/wave (2x B-fragment reuse), K+V staged via global_load_lds
// into XOR-swizzled LDS chunks, double-buffered, 1 barrier/iter.
// qkv: 64 output channels/block (x re-read 32x -> 4x).

typedef short short8 __attribute__((ext_vector_type(8)));
typedef short short4v __attribute__((ext_vector_type(4)));
typedef float f32x4 __attribute__((ext_vector_type(4)));

#define MFMA16(a, b, c) __builtin_amdgcn_mfma_f32_16x16x32_bf16((a), (b), (c), 0, 0, 0)

__device__ __forceinline__ unsigned short f2bf(float f) {
    union { float f; unsigned int u; } v;
    v.f = f;
    unsigned int u = v.u;
    return (unsigned short)((u + 0x7fffu + ((u >> 16) & 1u)) >> 16);
}

__device__ __forceinline__ void load_lds16(const unsigned short* g, unsigned short* l) {
    __builtin_amdgcn_global_load_lds(
        (const __attribute__((address_space(1))) unsigned int*)g,
        (__attribute__((address_space(3))) unsigned int*)l, 16, 0, 0);
}

// ---------------- Kernel 1: QKV projection (fp32 math, bf16 out) -------------
// Qc: [B][C][N]   Kr: [B][N][C]   Vc: [B][C][N]
__global__ __launch_bounds__(256, 1) void qkv_kernel(
    const float* __restrict__ x,
    const float* __restrict__ wq, const float* __restrict__ bq,
    const float* __restrict__ wk, const float* __restrict__ bk,
    const float* __restrict__ wv, const float* __restrict__ bv,
    unsigned short* __restrict__ Qc, unsigned short* __restrict__ Kr,
    unsigned short* __restrict__ Vc)
{
    const int C = 256, N = 4096;
    const int b  = blockIdx.z;
    const int o0 = blockIdx.y * 64;
    const int n  = blockIdx.x * 256 + threadIdx.x;

    float aq[64], ak[64], av[64];
#pragma unroll
    for (int i = 0; i < 64; i++) {
        aq[i] = bq[o0 + i];
        ak[i] = bk[o0 + i];
        av[i] = bv[o0 + i];
    }
    const float* xb = x + ((size_t)b * C) * N + n;
    for (int c = 0; c < C; c += 4) {
        float xv0 = xb[(size_t)(c + 0) * N];
        float xv1 = xb[(size_t)(c + 1) * N];
        float xv2 = xb[(size_t)(c + 2) * N];
        float xv3 = xb[(size_t)(c + 3) * N];
#pragma unroll
        for (int i = 0; i < 64; i++) {
            const float4 wqr = *(const float4*)(wq + (size_t)(o0 + i) * C + c);
            const float4 wkr = *(const float4*)(wk + (size_t)(o0 + i) * C + c);
            const float4 wvr = *(const float4*)(wv + (size_t)(o0 + i) * C + c);
            aq[i] = fmaf(wqr.x, xv0, fmaf(wqr.y, xv1, fmaf(wqr.z, xv2, fmaf(wqr.w, xv3, aq[i]))));
            ak[i] = fmaf(wkr.x, xv0, fmaf(wkr.y, xv1, fmaf(wkr.z, xv2, fmaf(wkr.w, xv3, ak[i]))));
            av[i] = fmaf(wvr.x, xv0, fmaf(wvr.y, xv1, fmaf(wvr.z, xv2, fmaf(wvr.w, xv3, av[i]))));
        }
    }
#pragma unroll
    for (int i = 0; i < 64; i++) {
        int o = o0 + i;
        Qc[((size_t)(b * C + o)) * N + n] = f2bf(aq[i]);
        Vc[((size_t)(b * C + o)) * N + n] = f2bf(av[i]);
        Kr[((size_t)(b * N + n)) * C + o] = f2bf(ak[i]);
    }
}

// ---------------- Kernel 2: flash attention + epilogue -----------------------
// 256 blocks x 256 threads (4 waves). b = bid&7, q0 = (bid>>3)*128 + wave*32.
// Each wave: 32 queries (two 16-row halves L/H sharing every K/V fragment).
// LDS per buffer: K chunks [key*32 + (j ^ (key&31))], V chunks [c*8 + (j ^ (c&7))],
// each chunk = 8 bf16 (16 B). Double-buffered, global_load_lds staging.
__global__ __launch_bounds__(256, 1) void attn_kernel(
    const unsigned short* __restrict__ Qc,
    const unsigned short* __restrict__ Kr,
    const unsigned short* __restrict__ Vc,
    const float* __restrict__ x,
    const float* __restrict__ gamma,
    float* __restrict__ out)
{
    const int C = 256, N = 4096;
    __shared__ __align__(16) unsigned short KV[2][32768];    // 128 KB: K @0, V @16384 (ush)
    __shared__ __align__(16) unsigned short Pt[4][32 * 68];  // per-wave P, row stride 68

    const int tid  = threadIdx.x;
    const int wave = tid >> 6;
    const int lane = tid & 63;
    const int quad = lane >> 4;
    const int l16  = lane & 15;
    const int bid  = blockIdx.x;
    const int b    = bid & 7;
    const int q0   = (bid >> 3) * 128 + wave * 32;

    const unsigned short* kb  = Kr + (size_t)b * N * C;   // [N][C]
    const unsigned short* vcb = Vc + (size_t)b * C * N;   // [C][N]

    // Q A-fragments for both halves (resident whole kernel)
    short8 aqL[8], aqH[8];
    {
        const unsigned short* qb = Qc + (size_t)b * C * N + q0 + l16;
#pragma unroll
        for (int f = 0; f < 8; f++) {
#pragma unroll
            for (int j = 0; j < 8; j++) {
                int c = f * 32 + quad * 8 + j;
                aqL[f][j] = (short)qb[(size_t)c * N];
                aqH[f][j] = (short)qb[(size_t)c * N + 16];
            }
        }
    }

    f32x4 oL[16], oH[16];
#pragma unroll
    for (int t = 0; t < 16; t++) {
        oL[t] = (f32x4){0.f, 0.f, 0.f, 0.f};
        oH[t] = (f32x4){0.f, 0.f, 0.f, 0.f};
    }
    float mL[4], lL[4], mH[4], lH[4];
#pragma unroll
    for (int r = 0; r < 4; r++) {
        mL[r] = -__builtin_inff(); lL[r] = 0.f;
        mH[r] = -__builtin_inff(); lH[r] = 0.f;
    }

    auto stage = [&](int buf, int m0) {
        unsigned short* dst = &KV[buf][0];
#pragma unroll
        for (int p = 0; p < 8; p++) {           // K: 2048 chunks
            int chunk = p * 256 + tid;
            int key = chunk >> 5;
            int j = (chunk & 31) ^ (key & 31);
            load_lds16(kb + (size_t)(m0 + key) * C + j * 8, dst + chunk * 8);
        }
#pragma unroll
        for (int p = 0; p < 8; p++) {           // V: 2048 chunks
            int chunk = p * 256 + tid;
            int c = chunk >> 3;
            int j = (chunk & 7) ^ (c & 7);
            load_lds16(vcb + (size_t)c * N + m0 + j * 8, dst + 16384 + chunk * 8);
        }
    };

    stage(0, 0);
    __syncthreads();

    const int xv0 = quad ^ (l16 & 7);   // V swizzle term for j=quad (j=quad+4 -> ^4)

    for (int it = 0; it < 128; ++it) {
        const int cur = it & 1;
        if (it < 127) stage(cur ^ 1, (it + 1) * 64);

        const unsigned short* Kb = &KV[cur][0];
        const unsigned short* Vb = &KV[cur][16384] + l16 * 64;

        // ---- S = Q K^T, both halves share every K fragment
        f32x4 sL[4], sH[4];
#pragma unroll
        for (int g = 0; g < 4; g++) {
            sL[g] = (f32x4){0.f, 0.f, 0.f, 0.f};
            sH[g] = (f32x4){0.f, 0.f, 0.f, 0.f};
        }
#pragma unroll
        for (int f = 0; f < 8; f++) {
#pragma unroll
            for (int g = 0; g < 4; g++) {
                int key = g * 16 + l16;
                int j = f * 4 + quad;
                int phys = key * 32 + (j ^ (key & 31));
                short8 kf = *(const short8*)(Kb + phys * 8);
                sL[g] = MFMA16(aqL[f], kf, sL[g]);
                sH[g] = MFMA16(aqH[f], kf, sH[g]);
            }
        }

        // ---- online softmax (rows quad*4+r; H rows stored at +16 in Pt)
        float aLr[4], aHr[4];
        unsigned short* PtW = &Pt[wave][0];
#pragma unroll
        for (int r = 0; r < 4; r++) {
            {
                float mx = fmaxf(fmaxf(sL[0][r], sL[1][r]), fmaxf(sL[2][r], sL[3][r]));
                mx = fmaxf(mx, __shfl_xor(mx, 1));
                mx = fmaxf(mx, __shfl_xor(mx, 2));
                mx = fmaxf(mx, __shfl_xor(mx, 4));
                mx = fmaxf(mx, __shfl_xor(mx, 8));
                float mn = fmaxf(mL[r], mx);
                float al = __expf(mL[r] - mn);
                mL[r] = mn;
                float e0 = __expf(sL[0][r] - mn);
                float e1 = __expf(sL[1][r] - mn);
                float e2 = __expf(sL[2][r] - mn);
                float e3 = __expf(sL[3][r] - mn);
                lL[r] = lL[r] * al + ((e0 + e1) + (e2 + e3));
                aLr[r] = al;
                unsigned short* pr = PtW + (quad * 4 + r) * 68 + l16;
                pr[0] = f2bf(e0); pr[16] = f2bf(e1); pr[32] = f2bf(e2); pr[48] = f2bf(e3);
            }
            {
                float mx = fmaxf(fmaxf(sH[0][r], sH[1][r]), fmaxf(sH[2][r], sH[3][r]));
                mx = fmaxf(mx, __shfl_xor(mx, 1));
                mx = fmaxf(mx, __shfl_xor(mx, 2));
                mx = fmaxf(mx, __shfl_xor(mx, 4));
                mx = fmaxf(mx, __shfl_xor(mx, 8));
                float mn = fmaxf(mH[r], mx);
                float al = __expf(mH[r] - mn);
                mH[r] = mn;
                float e0 = __expf(sH[0][r] - mn);
                float e1 = __expf(sH[1][r] - mn);
                float e2 = __expf(sH[2][r] - mn);
                float e3 = __expf(sH[3][r] - mn);
                lH[r] = lH[r] * al + ((e0 + e1) + (e2 + e3));
                aHr[r] = al;
                unsigned short* pr = PtW + (16 + quad * 4 + r) * 68 + l16;
                pr[0] = f2bf(e0); pr[16] = f2bf(e1); pr[32] = f2bf(e2); pr[48] = f2bf(e3);
            }
        }
        f32x4 aLv = (f32x4){aLr[0], aLr[1], aLr[2], aLr[3]};
        f32x4 aHv = (f32x4){aHr[0], aHr[1], aHr[2], aHr[3]};

        // ---- P -> A-layout (wave-private LDS, 2x b64 per frag: rows 136 B)
        const unsigned short* pbL = PtW + l16 * 68 + quad * 8;
        const unsigned short* pbH = PtW + (16 + l16) * 68 + quad * 8;
        short4v pL0a = *(const short4v*)(pbL);
        short4v pL0b = *(const short4v*)(pbL + 4);
        short4v pL1a = *(const short4v*)(pbL + 32);
        short4v pL1b = *(const short4v*)(pbL + 36);
        short4v pH0a = *(const short4v*)(pbH);
        short4v pH0b = *(const short4v*)(pbH + 4);
        short4v pH1a = *(const short4v*)(pbH + 32);
        short4v pH1b = *(const short4v*)(pbH + 36);
        short8 apL0 = __builtin_shufflevector(pL0a, pL0b, 0, 1, 2, 3, 4, 5, 6, 7);
        short8 apL1 = __builtin_shufflevector(pL1a, pL1b, 0, 1, 2, 3, 4, 5, 6, 7);
        short8 apH0 = __builtin_shufflevector(pH0a, pH0b, 0, 1, 2, 3, 4, 5, 6, 7);
        short8 apH1 = __builtin_shufflevector(pH1a, pH1b, 0, 1, 2, 3, 4, 5, 6, 7);

        // ---- rescale + PV; each V fragment feeds 4 MFMAs
#pragma unroll
        for (int t = 0; t < 16; t++) {
            short8 v0 = *(const short8*)(Vb + t * 1024 + xv0 * 8);
            short8 v1 = *(const short8*)(Vb + t * 1024 + (xv0 ^ 4) * 8);
            oL[t] *= aLv;
            oH[t] *= aHv;
            oL[t] = MFMA16(apL0, v0, oL[t]);
            oL[t] = MFMA16(apL1, v1, oL[t]);
            oH[t] = MFMA16(apH0, v0, oH[t]);
            oH[t] = MFMA16(apH1, v1, oH[t]);
        }
        __syncthreads();
    }

    // ---- epilogue: y = gamma * (O / l) + x
    const float g = gamma[0];
    float invL[4], invH[4];
#pragma unroll
    for (int r = 0; r < 4; r++) {
        float rs = lL[r];
        rs += __shfl_xor(rs, 1);
        rs += __shfl_xor(rs, 2);
        rs += __shfl_xor(rs, 4);
        rs += __shfl_xor(rs, 8);
        invL[r] = g / rs;
        float rh = lH[r];
        rh += __shfl_xor(rh, 1);
        rh += __shfl_xor(rh, 2);
        rh += __shfl_xor(rh, 4);
        rh += __shfl_xor(rh, 8);
        invH[r] = g / rh;
    }
#pragma unroll
    for (int t = 0; t < 16; t++) {
#pragma unroll
        for (int r = 0; r < 4; r++) {
            int c = t * 16 + l16;
            int nL = q0 + quad * 4 + r;
            int nH = nL + 16;
            size_t iL = ((size_t)(b * C + c)) * N + nL;
            size_t iH = ((size_t)(b * C + c)) * N + nH;
            out[iL] = fmaf(oL[t][r], invL[r], x[iL]);
            out[iH] = fmaf(oH[t][r], invH[r], x[iH]);
        }
    }
}

extern "C" void kernel_launch(void* const* d_in, const int* in_sizes, int n_in,
                              void* d_out, int out_size, void* d_ws, size_t ws_size,
                              hipStream_t stream) {
    const int B = 8, C = 256, N = 4096;
    const float* x     = (const float*)d_in[0];
    const float* wq    = (const float*)d_in[1];
    const float* bq    = (const float*)d_in[2];
    const float* wk    = (const float*)d_in[3];
    const float* bk    = (const float*)d_in[4];
    const float* wv    = (const float*)d_in[5];
    const float* bv    = (const float*)d_in[6];
    const float* gamma = (const float*)d_in[7];
    float* out = (float*)d_out;

    unsigned short* Qc = (unsigned short*)d_ws;             // [B][C][N] bf16
    unsigned short* Kr = Qc + (size_t)B * C * N;            // [B][N][C] bf16
    unsigned short* Vc = Kr + (size_t)B * C * N;            // [B][C][N] bf16

    qkv_kernel<<<dim3(N / 256, C / 64, B), 256, 0, stream>>>(
        x, wq, bq, wk, bk, wv, bv, Qc, Kr, Vc);
    attn_kernel<<<dim3(256), 256, 0, stream>>>(Qc, Kr, Vc, x, gamma, out);
}

// Round 4
// 413.732 us; speedup vs baseline: 3.9002x; 3.9002x over previous
//
#include <hip/hip_runtime.h>
#include <hip/hip_bf16.h>
#include <cstdint>

// B=8, C=256, N=4096 spatial self-attention.
// R3: qkv as bf16-MFMA GEMM (W pre-converted); attn = flash, KT=32,
// double-buffered global_load_lds staging, 8 waves/block (2/SIMD),
// alpha==1 rescale skip, corrected key iteration (exactly N keys).
// Layouts: Qr[B][N][C], Kr[B][N][C], Vc[B][C][N], Wb[3][256][256] (all bf16).

typedef short short8 __attribute__((ext_vector_type(8)));
typedef short short4v __attribute__((ext_vector_type(4)));
typedef float f32x4 __attribute__((ext_vector_type(4)));

#define MFMA16(a, b, c) __builtin_amdgcn_mfma_f32_16x16x32_bf16((a), (b), (c), 0, 0, 0)

__device__ __forceinline__ unsigned short f2bf(float f) {
    union { float f; unsigned int u; } v;
    v.f = f;
    unsigned int u = v.u;
    return (unsigned short)((u + 0x7fffu + ((u >> 16) & 1u)) >> 16);
}

__device__ __forceinline__ void load_lds16(const unsigned short* g, unsigned short* l) {
    __builtin_amdgcn_global_load_lds(
        (const __attribute__((address_space(1))) unsigned int*)g,
        (__attribute__((address_space(3))) unsigned int*)l, 16, 0, 0);
}

// ---------------- Kernel 0: weight fp32 -> bf16 ------------------------------
__global__ __launch_bounds__(256) void wcvt_kernel(
    const float* __restrict__ wq, const float* __restrict__ wk,
    const float* __restrict__ wv, unsigned short* __restrict__ Wb)
{
    int idx = (blockIdx.x * 256 + threadIdx.x) * 4;   // 0..196604
    const float* src = (idx < 65536) ? wq : ((idx < 131072) ? wk : wv);
    float4 f = *(const float4*)(src + (idx & 65535));
    short4v s = { (short)f2bf(f.x), (short)f2bf(f.y), (short)f2bf(f.z), (short)f2bf(f.w) };
    *(short4v*)(Wb + idx) = s;
}

// ---------------- Kernel 1: QKV projection via MFMA --------------------------
// 1024 blocks x 256 thr (4 waves). Block: batch b, 32 tokens; wave: 64 channels.
// acc[mat][ct][tt]: D[token][channel] tiles. 24 f32x4 = 96 VGPR.
__global__ __launch_bounds__(256, 2) void qkv_kernel(
    const float* __restrict__ x, const unsigned short* __restrict__ Wb,
    const float* __restrict__ bq, const float* __restrict__ bk,
    const float* __restrict__ bv,
    unsigned short* __restrict__ Qr, unsigned short* __restrict__ Kr,
    unsigned short* __restrict__ Vc)
{
    const int C = 256, N = 4096;
    __shared__ __align__(16) unsigned short Xt[32][264];   // [token][c], pad 264

    const int tid  = threadIdx.x;
    const int bid  = blockIdx.x;
    const int b    = bid >> 7;
    const int n0   = (bid & 127) * 32;
    const int wave = tid >> 6;
    const int lane = tid & 63;
    const int quad = lane >> 4;
    const int l16  = lane & 15;
    const int ch0  = wave * 64;

    // stage X^T tile: fp32 [c][token] -> bf16 LDS [token][c]
    {
        const int token = tid & 31;
        const int cg    = tid >> 5;                 // 0..7
        const float* xb = x + ((size_t)b * C) * N + n0 + token;
#pragma unroll
        for (int p = 0; p < 8; p++) {
            int c0 = p * 32 + cg * 4;
            float f0 = xb[(size_t)(c0 + 0) * N];
            float f1 = xb[(size_t)(c0 + 1) * N];
            float f2 = xb[(size_t)(c0 + 2) * N];
            float f3 = xb[(size_t)(c0 + 3) * N];
            short4v s = { (short)f2bf(f0), (short)f2bf(f1), (short)f2bf(f2), (short)f2bf(f3) };
            *(short4v*)(&Xt[token][c0]) = s;
        }
    }
    __syncthreads();

    f32x4 acc[3][4][2];
#pragma unroll
    for (int m = 0; m < 3; m++)
#pragma unroll
        for (int ct = 0; ct < 4; ct++)
#pragma unroll
            for (int tt = 0; tt < 2; tt++) acc[m][ct][tt] = (f32x4){0.f, 0.f, 0.f, 0.f};

#pragma unroll
    for (int kc = 0; kc < 8; kc++) {
        const int ko = kc * 32 + quad * 8;
        short8 ax0 = *(const short8*)(&Xt[l16][ko]);
        short8 ax1 = *(const short8*)(&Xt[16 + l16][ko]);
#pragma unroll
        for (int m = 0; m < 3; m++) {
#pragma unroll
            for (int ct = 0; ct < 4; ct++) {
                short8 wf = *(const short8*)(Wb + ((size_t)m << 16) +
                                             (ch0 + ct * 16 + l16) * 256 + ko);
                acc[m][ct][0] = MFMA16(ax0, wf, acc[m][ct][0]);
                acc[m][ct][1] = MFMA16(ax1, wf, acc[m][ct][1]);
            }
        }
    }

    // epilogue: + bias, cvt bf16, store. Q,K -> [N][C] (scalar), V -> [C][N] (b64)
#pragma unroll
    for (int ct = 0; ct < 4; ct++) {
        const int ch = ch0 + ct * 16 + l16;
        const float biq = bq[ch], bik = bk[ch], biv = bv[ch];
#pragma unroll
        for (int tt = 0; tt < 2; tt++) {
            const int tok0 = n0 + tt * 16 + quad * 4;
#pragma unroll
            for (int r = 0; r < 4; r++) {
                Qr[((size_t)b * N + tok0 + r) * C + ch] = f2bf(acc[0][ct][tt][r] + biq);
                Kr[((size_t)b * N + tok0 + r) * C + ch] = f2bf(acc[1][ct][tt][r] + bik);
            }
            short4v vs = { (short)f2bf(acc[2][ct][tt][0] + biv),
                           (short)f2bf(acc[2][ct][tt][1] + biv),
                           (short)f2bf(acc[2][ct][tt][2] + biv),
                           (short)f2bf(acc[2][ct][tt][3] + biv) };
            *(short4v*)(Vc + ((size_t)b * C + ch) * N + tok0) = vs;
        }
    }
}

// ---------------- Kernel 2: flash attention + epilogue -----------------------
// 256 blocks x 512 thr (8 waves, 2/SIMD). b = bid&7, q0 = (bid>>3)*128 + wave*16.
// KT=32 double-buffered; per buffer: K[32key][256c] swizzled @0, V[256c][32key] @8192.
// Fragment layouts (gfx950, verified):
//   A[m=lane&15][k=quad*8+j]  B[n=lane&15][k=quad*8+j]  C/D[row=quad*4+r][col=lane&15]
__global__ __launch_bounds__(512, 2) void attn_kernel(
    const unsigned short* __restrict__ Qr,
    const unsigned short* __restrict__ Kr,
    const unsigned short* __restrict__ Vc,
    const float* __restrict__ x,
    const float* __restrict__ gamma,
    float* __restrict__ out)
{
    const int C = 256, N = 4096;
    __shared__ __align__(16) unsigned short KV[2][16384];  // 64 KB total
    __shared__ __align__(16) unsigned short Pt[8][16 * 40]; // per-wave, stride 40

    const int tid  = threadIdx.x;
    const int wave = tid >> 6;
    const int lane = tid & 63;
    const int quad = lane >> 4;
    const int l16  = lane & 15;
    const int bid  = blockIdx.x;
    const int b    = bid & 7;
    const int q0   = (bid >> 3) * 128 + wave * 16;

    const unsigned short* kb  = Kr + (size_t)b * N * C;
    const unsigned short* vcb = Vc + (size_t)b * C * N;

    // Q A-fragments: b128 loads from Qr[N][C]
    short8 aq[8];
    {
        const unsigned short* qb = Qr + ((size_t)b * N + q0 + l16) * C;
#pragma unroll
        for (int f = 0; f < 8; f++)
            aq[f] = *(const short8*)(qb + f * 32 + quad * 8);
    }

    f32x4 o_acc[16];
#pragma unroll
    for (int t = 0; t < 16; t++) o_acc[t] = (f32x4){0.f, 0.f, 0.f, 0.f};
    float m_r[4], l_r[4];
#pragma unroll
    for (int r = 0; r < 4; r++) { m_r[r] = -__builtin_inff(); l_r[r] = 0.f; }

    auto stage = [&](int buf, int m0) {
        unsigned short* dst = &KV[buf][0];
#pragma unroll
        for (int p = 0; p < 2; p++) {               // K: 1024 chunks
            int chunk = p * 512 + tid;
            int key = chunk >> 5;
            int j = (chunk & 31) ^ (key & 31);
            load_lds16(kb + (size_t)(m0 + key) * C + j * 8, dst + chunk * 8);
        }
#pragma unroll
        for (int p = 0; p < 2; p++) {               // V: 1024 chunks
            int chunk = p * 512 + tid;
            int c = chunk >> 2;
            int j = (chunk & 3) ^ (c & 3);
            load_lds16(vcb + (size_t)c * N + m0 + j * 8, dst + 8192 + chunk * 8);
        }
    };

    stage(0, 0);
    __syncthreads();

    for (int it = 0; it < 128; ++it) {
        const int cur = it & 1;
        if (it < 127) stage(cur ^ 1, (it + 1) * 32);

        const unsigned short* Kb = &KV[cur][0];
        const unsigned short* Vb = &KV[cur][8192];

        // ---- S = Q K^T : 16 queries x 32 keys
        f32x4 s0 = (f32x4){0.f, 0.f, 0.f, 0.f};
        f32x4 s1 = (f32x4){0.f, 0.f, 0.f, 0.f};
#pragma unroll
        for (int f = 0; f < 8; f++) {
            const int j = f * 4 + quad;
            int k0 = l16;
            int k1 = 16 + l16;
            short8 kf0 = *(const short8*)(Kb + (k0 * 32 + (j ^ (k0 & 31))) * 8);
            short8 kf1 = *(const short8*)(Kb + (k1 * 32 + (j ^ (k1 & 31))) * 8);
            s0 = MFMA16(aq[f], kf0, s0);
            s1 = MFMA16(aq[f], kf1, s1);
        }

        // ---- online softmax (row = quad*4+r); alpha-skip when no max update
        float alpha[4];
        bool anyup = false;
        unsigned short* PtW = &Pt[wave][0];
#pragma unroll
        for (int r = 0; r < 4; r++) {
            float mx = fmaxf(s0[r], s1[r]);
            mx = fmaxf(mx, __shfl_xor(mx, 1));
            mx = fmaxf(mx, __shfl_xor(mx, 2));
            mx = fmaxf(mx, __shfl_xor(mx, 4));
            mx = fmaxf(mx, __shfl_xor(mx, 8));
            float mn = fmaxf(m_r[r], mx);
            anyup |= (mn > m_r[r]);
            float al = __expf(m_r[r] - mn);
            m_r[r] = mn;
            alpha[r] = al;
            float e0 = __expf(s0[r] - mn);
            float e1 = __expf(s1[r] - mn);
            l_r[r] = l_r[r] * al + (e0 + e1);
            unsigned short* pr = PtW + (quad * 4 + r) * 40 + l16;
            pr[0]  = f2bf(e0);
            pr[16] = f2bf(e1);
        }
        if (__any(anyup)) {
            f32x4 av = (f32x4){alpha[0], alpha[1], alpha[2], alpha[3]};
#pragma unroll
            for (int t = 0; t < 16; t++) o_acc[t] *= av;
        }

        // ---- P -> A-layout (wave-private LDS round trip, b128 aligned)
        short8 ap = *(const short8*)(PtW + l16 * 40 + quad * 8);

        // ---- PV: 16 channel-tiles
#pragma unroll
        for (int t = 0; t < 16; t++) {
            int c = t * 16 + l16;
            short8 vf = *(const short8*)(Vb + (c * 4 + (quad ^ (c & 3))) * 8);
            o_acc[t] = MFMA16(ap, vf, o_acc[t]);
        }
        __syncthreads();
    }

    // ---- epilogue: y = gamma * (O / l) + x  (float4 over 4 consecutive tokens)
    const float g = gamma[0];
    f32x4 inv;
#pragma unroll
    for (int r = 0; r < 4; r++) {
        float rs = l_r[r];
        rs += __shfl_xor(rs, 1);
        rs += __shfl_xor(rs, 2);
        rs += __shfl_xor(rs, 4);
        rs += __shfl_xor(rs, 8);
        inv[r] = g / rs;
    }
    const int nb = q0 + quad * 4;
#pragma unroll
    for (int t = 0; t < 16; t++) {
        int c = t * 16 + l16;
        size_t idx = ((size_t)(b * C + c)) * N + nb;
        f32x4 xv = *(const f32x4*)(x + idx);
        f32x4 ov = o_acc[t] * inv + xv;
        *(f32x4*)(out + idx) = ov;
    }
}

extern "C" void kernel_launch(void* const* d_in, const int* in_sizes, int n_in,
                              void* d_out, int out_size, void* d_ws, size_t ws_size,
                              hipStream_t stream) {
    const int B = 8, C = 256, N = 4096;
    const float* x     = (const float*)d_in[0];
    const float* wq    = (const float*)d_in[1];
    const float* bq    = (const float*)d_in[2];
    const float* wk    = (const float*)d_in[3];
    const float* bk    = (const float*)d_in[4];
    const float* wv    = (const float*)d_in[5];
    const float* bv    = (const float*)d_in[6];
    const float* gamma = (const float*)d_in[7];
    float* out = (float*)d_out;

    unsigned short* Qr = (unsigned short*)d_ws;             // [B][N][C] bf16
    unsigned short* Kr = Qr + (size_t)B * N * C;            // [B][N][C] bf16
    unsigned short* Vc = Kr + (size_t)B * N * C;            // [B][C][N] bf16
    unsigned short* Wb = Vc + (size_t)B * C * N;            // [3][256][256] bf16

    wcvt_kernel<<<dim3(192), 256, 0, stream>>>(wq, wk, wv, Wb);
    qkv_kernel<<<dim3(1024), 256, 0, stream>>>(x, Wb, bq, bk, bv, Qr, Kr, Vc);
    attn_kernel<<<dim3(256), 512, 0, stream>>>(Qr, Kr, Vc, x, gamma, out);
}

// Round 5
// 393.629 us; speedup vs baseline: 4.0994x; 1.0511x over previous
//
#include <hip/hip_runtime.h>
#include <hip/hip_bf16.h>
#include <cstdint>

// B=8, C=256, N=4096 spatial self-attention.
// R4: attn = 32 queries/wave (2x LDS amortization) + in-block key-split
// (waves 0-3 / 4-7 each take 2048 keys, LDS merge at end), KT=32 double-
// buffered global_load_lds staging, wave-wide base-2 online softmax with
// DPP max-reduction (no LDS-unit shuffles in hot loop).
// qkv: MFMA GEMM; Q scaled by log2e, stored [C][N] b64; K transposed via
// LDS -> coalesced [N][C] b128 stores; V [C][N] b64.

typedef short short8 __attribute__((ext_vector_type(8)));
typedef short short4v __attribute__((ext_vector_type(4)));
typedef float f32x4 __attribute__((ext_vector_type(4)));

#define MFMA16(a, b, c) __builtin_amdgcn_mfma_f32_16x16x32_bf16((a), (b), (c), 0, 0, 0)
#define LOG2E 1.4426950408889634f

__device__ __forceinline__ unsigned short f2bf(float f) {
    union { float f; unsigned int u; } v;
    v.f = f;
    unsigned int u = v.u;
    return (unsigned short)((u + 0x7fffu + ((u >> 16) & 1u)) >> 16);
}

__device__ __forceinline__ void load_lds16(const unsigned short* g, unsigned short* l) {
    __builtin_amdgcn_global_load_lds(
        (const __attribute__((address_space(1))) unsigned int*)g,
        (__attribute__((address_space(3))) unsigned int*)l, 16, 0, 0);
}

// max over the 16-lane row group via DPP row_ror (VALU only, no LDS unit)
__device__ __forceinline__ float rowmax16_dpp(float x) {
    int v;
    v = __builtin_amdgcn_update_dpp(0, __float_as_int(x), 0x121, 0xf, 0xf, false);
    x = fmaxf(x, __int_as_float(v));
    v = __builtin_amdgcn_update_dpp(0, __float_as_int(x), 0x122, 0xf, 0xf, false);
    x = fmaxf(x, __int_as_float(v));
    v = __builtin_amdgcn_update_dpp(0, __float_as_int(x), 0x124, 0xf, 0xf, false);
    x = fmaxf(x, __int_as_float(v));
    v = __builtin_amdgcn_update_dpp(0, __float_as_int(x), 0x128, 0xf, 0xf, false);
    x = fmaxf(x, __int_as_float(v));
    return x;
}

// ---------------- Kernel 0: weight fp32 -> bf16 ------------------------------
__global__ __launch_bounds__(256) void wcvt_kernel(
    const float* __restrict__ wq, const float* __restrict__ wk,
    const float* __restrict__ wv, unsigned short* __restrict__ Wb)
{
    int idx = (blockIdx.x * 256 + threadIdx.x) * 4;
    const float* src = (idx < 65536) ? wq : ((idx < 131072) ? wk : wv);
    float4 f = *(const float4*)(src + (idx & 65535));
    short4v s = { (short)f2bf(f.x), (short)f2bf(f.y), (short)f2bf(f.z), (short)f2bf(f.w) };
    *(short4v*)(Wb + idx) = s;
}

// ---------------- Kernel 1: QKV projection via MFMA --------------------------
// 1024 blocks x 256 thr (4 waves). Block: batch b, 32 tokens; wave: 64 channels.
// Qc [B][C][N] (pre-scaled by log2e), Kr [B][N][C], Vc [B][C][N].
__global__ __launch_bounds__(256, 2) void qkv_kernel(
    const float* __restrict__ x, const unsigned short* __restrict__ Wb,
    const float* __restrict__ bq, const float* __restrict__ bk,
    const float* __restrict__ bv,
    unsigned short* __restrict__ Qc, unsigned short* __restrict__ Kr,
    unsigned short* __restrict__ Vc)
{
    const int C = 256, N = 4096;
    __shared__ __align__(16) unsigned short Xt[32][264];   // [token][c], pad 264

    const int tid  = threadIdx.x;
    const int bid  = blockIdx.x;
    const int b    = bid >> 7;
    const int n0   = (bid & 127) * 32;
    const int wave = tid >> 6;
    const int lane = tid & 63;
    const int quad = lane >> 4;
    const int l16  = lane & 15;
    const int ch0  = wave * 64;

    // stage X^T tile: fp32 [c][token] -> bf16 LDS [token][c]
    {
        const int token = tid & 31;
        const int cg    = tid >> 5;
        const float* xb = x + ((size_t)b * C) * N + n0 + token;
#pragma unroll
        for (int p = 0; p < 8; p++) {
            int c0 = p * 32 + cg * 4;
            float f0 = xb[(size_t)(c0 + 0) * N];
            float f1 = xb[(size_t)(c0 + 1) * N];
            float f2 = xb[(size_t)(c0 + 2) * N];
            float f3 = xb[(size_t)(c0 + 3) * N];
            short4v s = { (short)f2bf(f0), (short)f2bf(f1), (short)f2bf(f2), (short)f2bf(f3) };
            *(short4v*)(&Xt[token][c0]) = s;
        }
    }
    __syncthreads();

    f32x4 acc[3][4][2];
#pragma unroll
    for (int m = 0; m < 3; m++)
#pragma unroll
        for (int ct = 0; ct < 4; ct++)
#pragma unroll
            for (int tt = 0; tt < 2; tt++) acc[m][ct][tt] = (f32x4){0.f, 0.f, 0.f, 0.f};

#pragma unroll
    for (int kc = 0; kc < 8; kc++) {
        const int ko = kc * 32 + quad * 8;
        short8 ax0 = *(const short8*)(&Xt[l16][ko]);
        short8 ax1 = *(const short8*)(&Xt[16 + l16][ko]);
#pragma unroll
        for (int m = 0; m < 3; m++) {
#pragma unroll
            for (int ct = 0; ct < 4; ct++) {
                short8 wf = *(const short8*)(Wb + ((size_t)m << 16) +
                                             (ch0 + ct * 16 + l16) * 256 + ko);
                acc[m][ct][0] = MFMA16(ax0, wf, acc[m][ct][0]);
                acc[m][ct][1] = MFMA16(ax1, wf, acc[m][ct][1]);
            }
        }
    }

    // ---- Q (scaled by log2e) and V: b64 stores to [C][N]
#pragma unroll
    for (int ct = 0; ct < 4; ct++) {
        const int ch = ch0 + ct * 16 + l16;
        const float biq = bq[ch], biv = bv[ch];
#pragma unroll
        for (int tt = 0; tt < 2; tt++) {
            const int tok0 = n0 + tt * 16 + quad * 4;
            short4v qs = { (short)f2bf((acc[0][ct][tt][0] + biq) * LOG2E),
                           (short)f2bf((acc[0][ct][tt][1] + biq) * LOG2E),
                           (short)f2bf((acc[0][ct][tt][2] + biq) * LOG2E),
                           (short)f2bf((acc[0][ct][tt][3] + biq) * LOG2E) };
            *(short4v*)(Qc + ((size_t)b * C + ch) * N + tok0) = qs;
            short4v vs = { (short)f2bf(acc[2][ct][tt][0] + biv),
                           (short)f2bf(acc[2][ct][tt][1] + biv),
                           (short)f2bf(acc[2][ct][tt][2] + biv),
                           (short)f2bf(acc[2][ct][tt][3] + biv) };
            *(short4v*)(Vc + ((size_t)b * C + ch) * N + tok0) = vs;
        }
    }

    // ---- K: transpose via LDS -> coalesced [N][C] b128 stores
    __syncthreads();    // Xt reads all done
#pragma unroll
    for (int ct = 0; ct < 4; ct++) {
        const int ch = ch0 + ct * 16 + l16;
        const float bik = bk[ch];
#pragma unroll
        for (int tt = 0; tt < 2; tt++) {
#pragma unroll
            for (int r = 0; r < 4; r++)
                Xt[tt * 16 + quad * 4 + r][ch] = f2bf(acc[1][ct][tt][r] + bik);
        }
    }
    __syncthreads();
#pragma unroll
    for (int p = 0; p < 2; p++) {
        int chunk = p * 256 + tid;          // 0..511
        int tok = chunk >> 4;
        int cc  = (chunk & 15) * 16;
        *(short8*)(Kr + ((size_t)b * N + n0 + tok) * C + cc) = *(const short8*)(&Xt[tok][cc]);
    }
}

// ---------------- Kernel 2: flash attention + epilogue -----------------------
// 256 blocks x 512 thr (8 waves, 2/SIMD). b = bid&7, q-block = (bid>>3)*128.
// Wave w: queries q0 = qblk + (w&3)*32 (halves L/H of 16), keys
// [(w>>2)*2048, +2048) in 64 iters of KT=32. In-block LDS merge of the two
// key-halves at the end. Fragment layouts (gfx950, verified):
//   A[m=lane&15][k=quad*8+j]  B[n=lane&15][k=quad*8+j]  C/D[row=quad*4+r][col=lane&15]
__global__ __launch_bounds__(512, 2) void attn_kernel(
    const unsigned short* __restrict__ Qc,
    const unsigned short* __restrict__ Kr,
    const unsigned short* __restrict__ Vc,
    const float* __restrict__ x,
    const float* __restrict__ gamma,
    float* __restrict__ out)
{
    const int C = 256, N = 4096;
    __shared__ __align__(16) unsigned short KV[2][32768];   // 128 KB
    __shared__ __align__(16) unsigned short Pt[8][1280];    // 32 rows x 40
    __shared__ float MlL[4][32];
    __shared__ float MwL[4];

    const int tid  = threadIdx.x;
    const int wave = tid >> 6;
    const int ks   = wave >> 2;          // key-split half
    const int w4   = wave & 3;
    const int lane = tid & 63;
    const int quad = lane >> 4;
    const int l16  = lane & 15;
    const int bid  = blockIdx.x;
    const int b    = bid & 7;
    const int q0   = (bid >> 3) * 128 + w4 * 32;

    const unsigned short* kb  = Kr + (size_t)b * N * C;
    const unsigned short* vcb = Vc + (size_t)b * C * N;

    // Q A-fragments (scalar loads from [C][N], once per kernel)
    short8 aqL[8], aqH[8];
    {
        const unsigned short* qb = Qc + (size_t)b * C * N + q0 + l16;
#pragma unroll
        for (int f = 0; f < 8; f++) {
#pragma unroll
            for (int j = 0; j < 8; j++) {
                size_t co = (size_t)(f * 32 + quad * 8 + j) * N;
                aqL[f][j] = (short)qb[co];
                aqH[f][j] = (short)qb[co + 16];
            }
        }
    }

    f32x4 oL[16], oH[16];
#pragma unroll
    for (int t = 0; t < 16; t++) {
        oL[t] = (f32x4){0.f, 0.f, 0.f, 0.f};
        oH[t] = (f32x4){0.f, 0.f, 0.f, 0.f};
    }
    float m_w = -__builtin_inff();
    float l_p[2][4];
#pragma unroll
    for (int h = 0; h < 2; h++)
#pragma unroll
        for (int r = 0; r < 4; r++) l_p[h][r] = 0.f;

    // stage both key-halves' K/V tiles (block-wide)
    auto stage = [&](int buf, int m0) {
        unsigned short* dst = &KV[buf][0];
#pragma unroll
        for (int p = 0; p < 4; p++) {               // K: 2048 chunks
            int chunk = p * 512 + tid;
            int half = chunk >> 10;
            int idx  = chunk & 1023;
            int key = idx >> 5;
            int j = (idx & 31) ^ (key & 31);
            load_lds16(kb + (size_t)(half * 2048 + m0 + key) * C + j * 8,
                       dst + half * 16384 + idx * 8);
        }
#pragma unroll
        for (int p = 0; p < 4; p++) {               // V: 2048 chunks
            int chunk = p * 512 + tid;
            int half = chunk >> 10;
            int idx  = chunk & 1023;
            int c = idx >> 2;
            int j = (idx & 3) ^ (c & 3);
            load_lds16(vcb + (size_t)c * N + half * 2048 + m0 + j * 8,
                       dst + half * 16384 + 8192 + idx * 8);
        }
    };

    stage(0, 0);
    __syncthreads();

    unsigned short* PtW = &Pt[wave][0];

    for (int it = 0; it < 64; ++it) {
        const int cur = it & 1;
        if (it < 63) stage(cur ^ 1, (it + 1) * 32);

        const unsigned short* Kb = &KV[cur][ks * 16384];
        const unsigned short* Vb = Kb + 8192;

        // ---- S = Q K^T : 32 queries x 32 keys
        f32x4 sL0 = {0.f,0.f,0.f,0.f}, sL1 = {0.f,0.f,0.f,0.f};
        f32x4 sH0 = {0.f,0.f,0.f,0.f}, sH1 = {0.f,0.f,0.f,0.f};
#pragma unroll
        for (int f = 0; f < 8; f++) {
            const int j = f * 4 + quad;
            int k0 = l16, k1 = 16 + l16;
            short8 kf0 = *(const short8*)(Kb + (k0 * 32 + (j ^ (k0 & 31))) * 8);
            short8 kf1 = *(const short8*)(Kb + (k1 * 32 + (j ^ (k1 & 31))) * 8);
            sL0 = MFMA16(aqL[f], kf0, sL0);
            sL1 = MFMA16(aqL[f], kf1, sL1);
            sH0 = MFMA16(aqH[f], kf0, sH0);
            sH1 = MFMA16(aqH[f], kf1, sH1);
        }

        // ---- wave-wide online max (base-2 logits; DPP + 2 shuffles)
        float mx = fmaxf(fmaxf(fmaxf(sL0[0], sL0[1]), fmaxf(sL0[2], sL0[3])),
                         fmaxf(fmaxf(sL1[0], sL1[1]), fmaxf(sL1[2], sL1[3])));
        mx = fmaxf(mx, fmaxf(fmaxf(fmaxf(sH0[0], sH0[1]), fmaxf(sH0[2], sH0[3])),
                             fmaxf(fmaxf(sH1[0], sH1[1]), fmaxf(sH1[2], sH1[3]))));
        mx = rowmax16_dpp(mx);
        mx = fmaxf(mx, __shfl_xor(mx, 16));
        mx = fmaxf(mx, __shfl_xor(mx, 32));
        const float mn = fmaxf(m_w, mx);
        const float al = exp2f(m_w - mn);
        const bool up = mn > m_w;
        m_w = mn;

        // ---- exps + P store (packed bf16 cvt), per-lane l partials
#pragma unroll
        for (int r = 0; r < 4; r++) {
            {
                float e0 = exp2f(sL0[r] - mn);
                float e1 = exp2f(sL1[r] - mn);
                l_p[0][r] = l_p[0][r] * al + (e0 + e1);
                union { __hip_bfloat162 v; unsigned int u; } cv;
                cv.v = __float22bfloat162_rn(float2{e0, e1});
                unsigned short* pr = PtW + (quad * 4 + r) * 40 + l16;
                pr[0]  = (unsigned short)(cv.u & 0xffff);
                pr[16] = (unsigned short)(cv.u >> 16);
            }
            {
                float e0 = exp2f(sH0[r] - mn);
                float e1 = exp2f(sH1[r] - mn);
                l_p[1][r] = l_p[1][r] * al + (e0 + e1);
                union { __hip_bfloat162 v; unsigned int u; } cv;
                cv.v = __float22bfloat162_rn(float2{e0, e1});
                unsigned short* pr = PtW + (16 + quad * 4 + r) * 40 + l16;
                pr[0]  = (unsigned short)(cv.u & 0xffff);
                pr[16] = (unsigned short)(cv.u >> 16);
            }
        }
        if (up) {
#pragma unroll
            for (int t = 0; t < 16; t++) { oL[t] *= al; oH[t] *= al; }
        }

        // ---- P -> A-layout (wave-private LDS)
        short8 apL = *(const short8*)(PtW + l16 * 40 + quad * 8);
        short8 apH = *(const short8*)(PtW + (16 + l16) * 40 + quad * 8);

        // ---- PV: 16 channel-tiles, each V fragment feeds both halves
#pragma unroll
        for (int t = 0; t < 16; t++) {
            int c = t * 16 + l16;
            short8 vf = *(const short8*)(Vb + (c * 4 + (quad ^ (c & 3))) * 8);
            oL[t] = MFMA16(apL, vf, oL[t]);
            oH[t] = MFMA16(apH, vf, oH[t]);
        }
        __syncthreads();
    }

    // ---- reduce l partials over the 16-lane row group
#pragma unroll
    for (int h = 0; h < 2; h++)
#pragma unroll
        for (int r = 0; r < 4; r++) {
            float rs = l_p[h][r];
            rs += __shfl_xor(rs, 1);
            rs += __shfl_xor(rs, 2);
            rs += __shfl_xor(rs, 4);
            rs += __shfl_xor(rs, 8);
            l_p[h][r] = rs;
        }

    // ---- in-block merge of the two key-halves
    float* CombF = (float*)(&KV[0][0]);   // 4 waves x 32 q x 256 c f32 = 128 KB
    __syncthreads();
    if (ks == 1) {
#pragma unroll
        for (int t = 0; t < 16; t++) {
#pragma unroll
            for (int r = 0; r < 4; r++) {
                CombF[(size_t)(w4 * 32 + quad * 4 + r) * 256 + t * 16 + l16] = oL[t][r];
                CombF[(size_t)(w4 * 32 + 16 + quad * 4 + r) * 256 + t * 16 + l16] = oH[t][r];
            }
        }
        if (l16 == 0) {
#pragma unroll
            for (int h = 0; h < 2; h++)
#pragma unroll
                for (int r = 0; r < 4; r++)
                    MlL[w4][h * 16 + quad * 4 + r] = l_p[h][r];
            if (lane == 0) MwL[w4] = m_w;
        }
    }
    __syncthreads();
    if (ks == 0) {
        const float g = gamma[0];
        const float m2w = MwL[w4];
        const float mt = fmaxf(m_w, m2w);
        const float f1 = exp2f(m_w - mt);
        const float f2 = exp2f(m2w - mt);
        float linv[2][4];
#pragma unroll
        for (int h = 0; h < 2; h++)
#pragma unroll
            for (int r = 0; r < 4; r++) {
                float l2 = MlL[w4][h * 16 + quad * 4 + r];
                linv[h][r] = g / (l_p[h][r] * f1 + l2 * f2);
            }
#pragma unroll
        for (int t = 0; t < 16; t++) {
            const int c = t * 16 + l16;
#pragma unroll
            for (int h = 0; h < 2; h++) {
                const int nb = q0 + h * 16 + quad * 4;
                f32x4 o1 = h ? oH[t] : oL[t];
                f32x4 ov;
#pragma unroll
                for (int r = 0; r < 4; r++) {
                    float o2 = CombF[(size_t)(w4 * 32 + h * 16 + quad * 4 + r) * 256 + c];
                    ov[r] = (o1[r] * f1 + o2 * f2) * linv[h][r];
                }
                size_t idx = ((size_t)(b * C + c)) * N + nb;
                f32x4 xv = *(const f32x4*)(x + idx);
                *(f32x4*)(out + idx) = ov + xv;
            }
        }
    }
}

extern "C" void kernel_launch(void* const* d_in, const int* in_sizes, int n_in,
                              void* d_out, int out_size, void* d_ws, size_t ws_size,
                              hipStream_t stream) {
    const int B = 8, C = 256, N = 4096;
    const float* x     = (const float*)d_in[0];
    const float* wq    = (const float*)d_in[1];
    const float* bq    = (const float*)d_in[2];
    const float* wk    = (const float*)d_in[3];
    const float* bk    = (const float*)d_in[4];
    const float* wv    = (const float*)d_in[5];
    const float* bv    = (const float*)d_in[6];
    const float* gamma = (const float*)d_in[7];
    float* out = (float*)d_out;

    unsigned short* Qc = (unsigned short*)d_ws;             // [B][C][N] bf16 (x log2e)
    unsigned short* Kr = Qc + (size_t)B * C * N;            // [B][N][C] bf16
    unsigned short* Vc = Kr + (size_t)B * N * C;            // [B][C][N] bf16
    unsigned short* Wb = Vc + (size_t)B * C * N;            // [3][256][256] bf16

    wcvt_kernel<<<dim3(192), 256, 0, stream>>>(wq, wk, wv, Wb);
    qkv_kernel<<<dim3(1024), 256, 0, stream>>>(x, Wb, bq, bk, bv, Qc, Kr, Vc);
    attn_kernel<<<dim3(256), 512, 0, stream>>>(Qc, Kr, Vc, x, gamma, out);
}